// Round 8
// baseline (162.788 us; speedup 1.0000x reference)
//
#include <hip/hip_runtime.h>
#include <math.h>

#define B_TOT 2048
#define IN_TOT 512
#define OUT_TOT 512
#define COLS 64       // cols per block = lanes per wave
#define ROWS 32       // rows per block
#define KOCT 64       // k-range per wave (octant)
#define RB 8          // rows per combine batch

__global__ __launch_bounds__(512, 2) void morph_kernel(
    const float* __restrict__ x,
    const float* __restrict__ wdil,
    const float* __restrict__ wero,
    float* __restrict__ out)
{
    // partial buffers for the 8 k-octant waves, 8 rows per batch: 2 x 16 KB
    __shared__ float pd[8][RB][COLS];
    __shared__ float pe[8][RB][COLS];

    const int tid  = (int)threadIdx.x;
    const int lane = tid & 63;
    const int wv   = __builtin_amdgcn_readfirstlane(tid >> 6);  // k-octant

    const int col0 = (int)blockIdx.x * COLS;
    const int row0 = (int)blockIdx.y * ROWS;
    const int col  = col0 + lane;

    // ---- stage this lane's column weights for its k-octant: 128 VGPRs ----
    float4 wd[16], we[16];
    {
        const float* wdp = wdil + (size_t)col * IN_TOT + wv * KOCT;
        const float* wep = wero + (size_t)col * IN_TOT + wv * KOCT;
#pragma unroll
        for (int i = 0; i < 16; ++i) {
            wd[i] = *(const float4*)(wdp + i * 4);
            we[i] = *(const float4*)(wep + i * 4);
        }
    }

    const float* xoct = x + (size_t)row0 * IN_TOT + wv * KOCT;

#pragma unroll 1
    for (int rb = 0; rb < ROWS / RB; ++rb) {
#pragma unroll 1
        for (int j = 0; j < RB; ++j) {
            // wave-uniform x row segment: 16 broadcast loads (1 line each)
            const float* xr = xoct + (size_t)(rb * RB + j) * IN_TOT;
            float4 xb[16];
#pragma unroll
            for (int i = 0; i < 16; ++i)
                xb[i] = *(const float4*)(xr + i * 4);

            float dil = -INFINITY, ero = INFINITY;
#pragma unroll
            for (int i = 0; i < 16; ++i) {
                float4 a = xb[i], u = wd[i], v = we[i];
                dil = fmaxf(fmaxf(a.x + u.x, a.y + u.y), dil);   // v_max3
                dil = fmaxf(fmaxf(a.z + u.z, a.w + u.w), dil);
                ero = fminf(fminf(a.x - v.x, a.y - v.y), ero);   // v_min3
                ero = fminf(fminf(a.z - v.z, a.w - v.w), ero);
            }
            pd[wv][j][lane] = dil;      // contiguous 256B per wave: conflict-free
            pe[wv][j][lane] = ero;
        }
        __syncthreads();

        // ---- combine 8 octant partials for this 8-row batch ----
        {
            const int r = tid >> 6;     // 0..7 (wave index = row in batch)
            const int c = tid & 63;
            float d = pd[0][r][c], e = pe[0][r][c];
#pragma unroll
            for (int w2 = 1; w2 < 8; ++w2) {
                d = fmaxf(d, pd[w2][r][c]);   // exact: max is associative
                e = fminf(e, pe[w2][r][c]);
            }
            out[(size_t)(row0 + rb * RB + r) * OUT_TOT + col0 + c] = d + e;
        }
        __syncthreads();
    }
}

extern "C" void kernel_launch(void* const* d_in, const int* in_sizes, int n_in,
                              void* d_out, int out_size, void* d_ws, size_t ws_size,
                              hipStream_t stream)
{
    const float* x  = (const float*)d_in[0];
    const float* wd = (const float*)d_in[1];
    const float* we = (const float*)d_in[2];
    float* out = (float*)d_out;

    dim3 grid(OUT_TOT / COLS, B_TOT / ROWS);   // (8, 64) = 512 blocks
    dim3 block(512);                           // 8 waves = 8 k-octants
    hipLaunchKernelGGL(morph_kernel, grid, block, 0, stream, x, wd, we, out);
}